// Round 15
// baseline (140.014 us; speedup 1.0000x reference)
//
#include <hip/hip_runtime.h>
#include <hip/hip_fp16.h>

typedef __attribute__((ext_vector_type(8))) _Float16 f16x8;
typedef __attribute__((ext_vector_type(4))) float f32x4;
typedef __attribute__((ext_vector_type(4))) unsigned int u32x4;

__device__ __forceinline__ unsigned short f2h(float f) {
  __half h = __float2half(f);
  return __builtin_bit_cast(unsigned short, h);
}
__device__ __forceinline__ __half2 bc_h2(unsigned u) {
  return __builtin_bit_cast(__half2, u);
}

// ---------------------------------------------------------------------------
// Kernel A: prep. blocks 0..511: x NCHW fp32 -> NHWC fp16 xt[b][h][w][c].
// blocks 512..871: repack main_w -> wt[k][128][64], offset_w -> wot[k][32][64].
// ---------------------------------------------------------------------------
__global__ __launch_bounds__(256) void prep_all(
    const float* __restrict__ x, const float* __restrict__ mw,
    const float* __restrict__ ow, unsigned short* __restrict__ xt,
    unsigned short* __restrict__ wt, unsigned short* __restrict__ wot) {
  __shared__ float tile[64 * 129];
  int blk = blockIdx.x;
  int t = threadIdx.x;
  if (blk < 512) {
    const float* xrow = x + ((long)(blk >> 7) << 20) + ((blk & 127) << 7);
#pragma unroll
    for (int i = 0; i < 32; ++i) {
      int idx = t + (i << 8);          // c = idx>>7, w = idx&127
      tile[(idx >> 7) * 129 + (idx & 127)] =
          xrow[((long)(idx >> 7) << 14) + (idx & 127)];
    }
    __syncthreads();
    unsigned short* orow = xt + ((long)blk << 13);
#pragma unroll
    for (int i = 0; i < 32; ++i) {
      int idx = t + (i << 8);          // w = idx>>6, c = idx&63
      orow[idx] = f2h(tile[(idx & 63) * 129 + (idx >> 6)]);
    }
  } else {
    int idx = (blk - 512) * 256 + t;   // 0..92159
    if (idx < 73728) {
      int c = idx & 63;
      int o = (idx >> 6) & 127;
      int k = idx >> 13;
      wt[idx] = f2h(mw[o * 576 + c * 9 + k]);
    } else {
      int i2 = idx - 73728;
      int c = i2 & 63;
      int o = (i2 >> 6) & 31;
      int k = i2 >> 11;
      wot[i2] = (o < 18) ? f2h(ow[o * 576 + c * 9 + k]) : (unsigned short)0;
    }
  }
}

// ---------------------------------------------------------------------------
// Kernel B: offset conv 64->18 via f16 MFMA (64-px blocks, grid 1024).
// ---------------------------------------------------------------------------
__global__ __launch_bounds__(256) void offs_mfma(
    const unsigned short* __restrict__ xt, const unsigned short* __restrict__ wot,
    const float* __restrict__ ob, float* __restrict__ offs) {
  int l = blockIdx.x;
  int bid = ((l & 7) << 7) + (l >> 3);   // XCD swizzle
  int b = bid >> 8;
  int r8 = bid & 255;
  int h = r8 >> 1;
  int w0 = (r8 & 1) << 6;
  int t = threadIdx.x;
  int lane = t & 63;
  int wv = t >> 6;
  int l15 = lane & 15;
  int l4 = lane >> 4;
  int l4k = l4 << 3;

  f32x4 oacc[2];
  oacc[0] = f32x4{0.f, 0.f, 0.f, 0.f};
  oacc[1] = f32x4{0.f, 0.f, 0.f, 0.f};

  const unsigned short* xb = xt + ((long)b << 20);
  const unsigned short* wkb = wot + (l15 << 6) + l4k;

#pragma unroll 1
  for (int k = 0; k < 9; ++k) {
    int ky = k / 3, kx = k - 3 * ky;
    int y = h + ky - 1;
    bool yok = (unsigned)y < 128u;
    int yc = min(max(y, 0), 127);
    const unsigned short* xrow = xb + ((long)yc << 13);
    int px = w0 + (wv << 4) + l15 + kx - 1;
    bool pv = yok && ((unsigned)px < 128u);
    int pxo = min(max(px, 0), 127) << 6;
#pragma unroll
    for (int c0 = 0; c0 < 64; c0 += 32) {
      f16x8 bv = *(const f16x8*)(xrow + pxo + c0 + l4k);
      if (!pv) bv = f16x8{0, 0, 0, 0, 0, 0, 0, 0};
#pragma unroll
      for (int m = 0; m < 2; ++m) {
        f16x8 af = *(const f16x8*)(wkb + (k << 11) + (m << 10) + c0);
        oacc[m] = __builtin_amdgcn_mfma_f32_16x16x32_f16(af, bv, oacc[m], 0, 0, 0);
      }
    }
  }

#pragma unroll
  for (int m = 0; m < 2; ++m) {
#pragma unroll
    for (int r = 0; r < 4; ++r) {
      int oc = (m << 4) + (l4 << 2) + r;
      if (oc < 18)
        offs[((long)(b * 18 + oc) << 14) + (h << 7) + w0 + (wv << 4) + l15] =
            oacc[m][r] + ob[oc];
    }
  }
}

// ---------------------------------------------------------------------------
// Kernel C: deformable conv, zero-barrier register-V pipeline.
// Block = 64-px half-row, 4 waves, grid 1024. Wave wv owns px column
// [w0+wv*16,+16) x ALL 128 out-ch (8 m-frags). Lane (l15=px, l4=c-chunk)
// gathers its own B-fragment corners into g[2][8] (depth-1 dbuf, fully
// unrolled -> literal indices). Per tap: AF(k) -> SB -> ISSUE(k+1) -> SB ->
// CONSUME(k). vmcnt order: af(k) older than g(k+1), so MFMA's af-wait
// leaves next gathers in flight. No launch_bounds cap (spill canary:
// WRITE_SIZE must stay ~32.8 MB). LDS: 9 KB wtab, one barrier total.
// ---------------------------------------------------------------------------
__global__ __launch_bounds__(256) void deform_mfma(
    const unsigned short* __restrict__ xt, const float* __restrict__ offs,
    const unsigned short* __restrict__ wt, const float* __restrict__ mb,
    float* __restrict__ out) {
  __shared__ uint4 wtab[9][64];

  int l = blockIdx.x;
  int bid = ((l & 7) << 7) + (l >> 3);   // XCD swizzle
  int b = bid >> 8;
  int r8 = bid & 255;
  int h = r8 >> 1;
  int w0 = (r8 & 1) << 6;
  int t = threadIdx.x;
  int lane = t & 63;
  int wv = t >> 6;
  int l15 = lane & 15;
  int l4 = lane >> 4;
  int l4k = l4 << 3;
  int pxf = (wv << 4) + l15;             // px-in-tile this lane serves

  // ---- sampling table: 576 = 9 taps x 64 px (one barrier) ----
  const float* ob_ = offs + ((long)(b * 18) << 14) + (h << 7) + w0;
  for (int idx = t; idx < 576; idx += 256) {
    int px = idx & 63, k = idx >> 6;
    int ky = k / 3, kx = k - 3 * ky;
    float dy = ob_[((2 * k) << 14) + px];
    float dx = ob_[((2 * k + 1) << 14) + px];
    float py = (float)(h - 1 + ky) + dy;
    float pxq = (float)(w0 + px - 1 + kx) + dx;
    float fy = floorf(py), fx = floorf(pxq);
    float wy = py - fy, wx = pxq - fx;
    int y0 = (int)fy, x0 = (int)fx;
    int y1 = y0 + 1, x1 = x0 + 1;
    bool vy0 = (unsigned)y0 < 128u, vy1 = (unsigned)y1 < 128u;
    bool vx0 = (unsigned)x0 < 128u, vx1 = (unsigned)x1 < 128u;
    float w00 = (vy0 && vx0) ? (1.f - wy) * (1.f - wx) : 0.f;
    float w01 = (vy0 && vx1) ? (1.f - wy) * wx : 0.f;
    float w10 = (vy1 && vx0) ? wy * (1.f - wx) : 0.f;
    float w11 = (vy1 && vx1) ? wy * wx : 0.f;
    int y0c = min(max(y0, 0), 127), y1c = min(max(y1, 0), 127);
    int x0c = min(max(x0, 0), 127), x1c = min(max(x1, 0), 127);
    wtab[k][px] = make_uint4(
        (unsigned)f2h(w00) | ((unsigned)f2h(w01) << 16),
        (unsigned)f2h(w10) | ((unsigned)f2h(w11) << 16),
        (unsigned)(unsigned short)y0c | ((unsigned)(unsigned short)y1c << 16),
        (unsigned)(unsigned short)x0c | ((unsigned)(unsigned short)x1c << 16));
  }
  __syncthreads();

  const unsigned short* xb = xt + ((long)b << 20);

  f32x4 acc[8];
#pragma unroll
  for (int m = 0; m < 8; ++m) acc[m] = f32x4{0.f, 0.f, 0.f, 0.f};

  f16x8 af[8][2];
  u32x4 g[2][8];

  // ---- prologue: issue tap-0 gathers ----
  {
    uint4 e = wtab[0][pxf];
    int y0 = (int)(short)(e.z & 0xffff), y1 = (int)(short)(e.z >> 16);
    int x0 = (int)(short)(e.w & 0xffff), x1 = (int)(short)(e.w >> 16);
    const unsigned short* r0 = xb + (y0 << 13) + l4k;
    const unsigned short* r1 = xb + (y1 << 13) + l4k;
    int o0 = x0 << 6, o1 = x1 << 6;
    g[0][0] = *(const u32x4*)(r0 + o0);
    g[0][1] = *(const u32x4*)(r0 + o1);
    g[0][2] = *(const u32x4*)(r1 + o0);
    g[0][3] = *(const u32x4*)(r1 + o1);
    g[0][4] = *(const u32x4*)(r0 + o0 + 32);
    g[0][5] = *(const u32x4*)(r0 + o1 + 32);
    g[0][6] = *(const u32x4*)(r1 + o0 + 32);
    g[0][7] = *(const u32x4*)(r1 + o1 + 32);
  }

#pragma unroll
  for (int k = 0; k < 9; ++k) {
    // ---- AF(k): 16 weight fragments (before gathers k+1 in vmcnt order) ----
#pragma unroll
    for (int m = 0; m < 8; ++m)
#pragma unroll
      for (int c0 = 0; c0 < 2; ++c0)
        af[m][c0] = *(const f16x8*)(
            wt + (((k << 7) + (m << 4) + l15) << 6) + (c0 << 5) + l4k);
    __builtin_amdgcn_sched_barrier(0);

    // ---- ISSUE(k+1) ----
    if (k < 8) {
      uint4 e = wtab[k + 1][pxf];
      int y0 = (int)(short)(e.z & 0xffff), y1 = (int)(short)(e.z >> 16);
      int x0 = (int)(short)(e.w & 0xffff), x1 = (int)(short)(e.w >> 16);
      const unsigned short* r0 = xb + (y0 << 13) + l4k;
      const unsigned short* r1 = xb + (y1 << 13) + l4k;
      int o0 = x0 << 6, o1 = x1 << 6;
#pragma unroll
      for (int q = 0; q < 1; ++q) {   // scope
        g[(k + 1) & 1][0] = *(const u32x4*)(r0 + o0);
        g[(k + 1) & 1][1] = *(const u32x4*)(r0 + o1);
        g[(k + 1) & 1][2] = *(const u32x4*)(r1 + o0);
        g[(k + 1) & 1][3] = *(const u32x4*)(r1 + o1);
        g[(k + 1) & 1][4] = *(const u32x4*)(r0 + o0 + 32);
        g[(k + 1) & 1][5] = *(const u32x4*)(r0 + o1 + 32);
        g[(k + 1) & 1][6] = *(const u32x4*)(r1 + o0 + 32);
        g[(k + 1) & 1][7] = *(const u32x4*)(r1 + o1 + 32);
      }
    }
    __builtin_amdgcn_sched_barrier(0);

    // ---- CONSUME(k): bilinear + 16 MFMAs ----
    {
      uint4 e = wtab[k][pxf];
      __half2 w00 = bc_h2((e.x & 0xffffu) | (e.x << 16));
      __half2 w01 = bc_h2((e.x >> 16) | (e.x & 0xffff0000u));
      __half2 w10 = bc_h2((e.y & 0xffffu) | (e.y << 16));
      __half2 w11 = bc_h2((e.y >> 16) | (e.y & 0xffff0000u));
#pragma unroll
      for (int ch = 0; ch < 2; ++ch) {
        u32x4 rr;
#pragma unroll
        for (int j = 0; j < 4; ++j) {
          __half2 v = __hmul2(w00, bc_h2(g[k & 1][ch * 4 + 0][j]));
          v = __hfma2(w01, bc_h2(g[k & 1][ch * 4 + 1][j]), v);
          v = __hfma2(w10, bc_h2(g[k & 1][ch * 4 + 2][j]), v);
          v = __hfma2(w11, bc_h2(g[k & 1][ch * 4 + 3][j]), v);
          rr[j] = __builtin_bit_cast(unsigned, v);
        }
        f16x8 bv = __builtin_bit_cast(f16x8, rr);
#pragma unroll
        for (int m = 0; m < 8; ++m)
          acc[m] = __builtin_amdgcn_mfma_f32_16x16x32_f16(
              af[m][ch], bv, acc[m], 0, 0, 0);
      }
    }
  }

  // ---- epilogue: D row = o (lane>>4)*4+reg, col = px (lane&15) ----
  int hw0 = (h << 7) + w0 + (wv << 4);
#pragma unroll
  for (int m = 0; m < 8; ++m) {
    int orow = (m << 4) + (l4 << 2);
#pragma unroll
    for (int r = 0; r < 4; ++r)
      out[((long)(b * 128 + orow + r) << 14) + hw0 + l15] =
          acc[m][r] + mb[orow + r];
  }
}

extern "C" void kernel_launch(void* const* d_in, const int* in_sizes, int n_in,
                              void* d_out, int out_size, void* d_ws, size_t ws_size,
                              hipStream_t stream) {
  const float* x  = (const float*)d_in[0];
  const float* ow = (const float*)d_in[1];
  const float* ob = (const float*)d_in[2];
  const float* mw = (const float*)d_in[3];
  const float* mb = (const float*)d_in[4];
  float* out  = (float*)d_out;
  unsigned short* xt  = (unsigned short*)d_ws;                      // 8 MB
  unsigned short* wt  = (unsigned short*)((char*)d_ws + 8388608);   // 144 KB
  unsigned short* wot = (unsigned short*)((char*)d_ws + 8536064);   // 36 KB
  float* offs = (float*)((char*)d_ws + 8572928);                    // 4.5 MB

  prep_all<<<872, 256, 0, stream>>>(x, mw, ow, xt, wt, wot);
  offs_mfma<<<1024, 256, 0, stream>>>(xt, wot, ob, offs);
  deform_mfma<<<1024, 256, 0, stream>>>(xt, offs, wt, mb, out);
}